// Round 1
// baseline (1335.439 us; speedup 1.0000x reference)
//
// DeltaNet forward, MI355X/gfx950. Round 1: correct + MFMA everywhere matmul-shaped.
// Pipeline: cvt/transpose -> beta/floor -> QKV GEMMs -> conv+silu+l2norm ->
// fus GEMM+gelu -> fus2 -> UT transform (chunk-parallel, packs MFMA frags) ->
// dv-sliced MFMA scan -> FIR+gating+double-RMS -> output GEMM.
#include <hip/hip_runtime.h>
#include <hip/hip_bf16.h>
#include <cstdint>
#include <cstddef>

#define DEVI static __device__ __forceinline__

typedef __attribute__((ext_vector_type(4))) float f32x4;
typedef __attribute__((ext_vector_type(8))) short s16x8;
typedef unsigned short u16;
typedef unsigned int u32;

DEVI float bf2f(u16 u){ u32 x = ((u32)u) << 16; float f; __builtin_memcpy(&f, &x, 4); return f; }
DEVI u16 f2bf(float f){ u32 x; __builtin_memcpy(&x, &f, 4); u32 r = x + 0x7fffu + ((x >> 16) & 1u); return (u16)(r >> 16); }
DEVI float sigm(float x){ return 1.0f / (1.0f + expf(-x)); }
DEVI f32x4 mfma16(s16x8 a, s16x8 b, f32x4 c){ return __builtin_amdgcn_mfma_f32_16x16x32_bf16(a, b, c, 0, 0, 0); }
DEVI s16x8 pack8(float4 a, float4 b){
  s16x8 v;
  v[0]=(short)f2bf(a.x); v[1]=(short)f2bf(a.y); v[2]=(short)f2bf(a.z); v[3]=(short)f2bf(a.w);
  v[4]=(short)f2bf(b.x); v[5]=(short)f2bf(b.y); v[6]=(short)f2bf(b.z); v[7]=(short)f2bf(b.w);
  return v;
}

// ---------------- convert fp32 -> bf16 (vectorized) ----------------
__global__ __launch_bounds__(256) void cvt_bf16_k(const float* __restrict__ src, u16* __restrict__ dst, int n4){
  int i = blockIdx.x * 256 + threadIdx.x;
  if (i < n4){
    float4 v = ((const float4*)src)[i];
    ushort4 o; o.x = f2bf(v.x); o.y = f2bf(v.y); o.z = f2bf(v.z); o.w = f2bf(v.w);
    ((ushort4*)dst)[i] = o;
  }
}

// ---------------- transpose fp32 [K][N] -> bf16 [N][K] ----------------
__global__ __launch_bounds__(256) void transpose_bf16_k(const float* __restrict__ src, u16* __restrict__ dst, int K, int N){
  __shared__ float tile[32][33];
  const int n0 = blockIdx.x * 32, k0 = blockIdx.y * 32;
  const int t = threadIdx.x, cc = t & 31, rb = t >> 5;
  #pragma unroll
  for (int it = 0; it < 4; ++it){ int rr = rb + it*8; tile[rr][cc] = src[(size_t)(k0+rr)*N + n0 + cc]; }
  __syncthreads();
  #pragma unroll
  for (int it = 0; it < 4; ++it){ int rr = rb + it*8; dst[(size_t)(n0+rr)*K + k0 + cc] = f2bf(tile[cc][rr]); }
}

// ---------------- GEMM: A[M][K]bf16 @ Bt[N][K]bf16 -> C[M][N] ----------------
// 128x128 tile, BK=64, 4 waves (2x2), 4x4 16x16 frags/wave, XOR-swizzled LDS.
// EPI: 0 = store bf16, 1 = +bias, exact gelu, store bf16, 2 = store fp32.
template<int EPI>
__global__ __launch_bounds__(256, 2) void gemm_bt(
    const u16* __restrict__ A, const u16* __restrict__ Bt, void* __restrict__ Cout,
    const float* __restrict__ bias, int M, int N, int K)
{
  __shared__ __align__(16) u16 As[128*64];
  __shared__ __align__(16) u16 Bs[128*64];
  const int t = threadIdx.x;
  const int lane = t & 63, w = t >> 6;
  const int wr = w >> 1, wc = w & 1;
  const int g = lane >> 4, r16 = lane & 15;
  const int m0 = blockIdx.y * 128, n0 = blockIdx.x * 128;
  f32x4 acc[4][4];
  #pragma unroll
  for (int i=0;i<4;++i){ f32x4 z = {0,0,0,0}; acc[i][0]=z; acc[i][1]=z; acc[i][2]=z; acc[i][3]=z; }
  int4 pre[8];
  const int NK = K / 64;
  // prefetch k-tile 0
  #pragma unroll
  for (int j=0;j<4;++j){
    int slot = j*256 + t, row = slot >> 3, ch = slot & 7;
    pre[j]   = *(const int4*)(A  + (size_t)(m0+row)*K + ch*8);
    pre[4+j] = *(const int4*)(Bt + (size_t)(n0+row)*K + ch*8);
  }
  for (int kt = 0; kt < NK; ++kt){
    __syncthreads();                     // previous tile fully consumed
    #pragma unroll
    for (int j=0;j<4;++j){
      int slot = j*256 + t, row = slot >> 3, ch = slot & 7;
      int swz = (ch ^ (row & 7)) * 16;
      *(int4*)((char*)As + row*128 + swz) = pre[j];
      *(int4*)((char*)Bs + row*128 + swz) = pre[4+j];
    }
    __syncthreads();                     // tile visible
    if (kt + 1 < NK){
      #pragma unroll
      for (int j=0;j<4;++j){
        int slot = j*256 + t, row = slot >> 3, ch = slot & 7;
        pre[j]   = *(const int4*)(A  + (size_t)(m0+row)*K + (kt+1)*64 + ch*8);
        pre[4+j] = *(const int4*)(Bt + (size_t)(n0+row)*K + (kt+1)*64 + ch*8);
      }
    }
    #pragma unroll
    for (int kh = 0; kh < 2; ++kh){
      s16x8 af[4], bf_[4];
      #pragma unroll
      for (int i=0;i<4;++i){
        int arow = wr*64 + i*16 + r16;
        af[i]  = *(const s16x8*)((const char*)As + arow*128 + (((4*kh+g) ^ (arow&7))*16));
        int brow = wc*64 + i*16 + r16;
        bf_[i] = *(const s16x8*)((const char*)Bs + brow*128 + (((4*kh+g) ^ (brow&7))*16));
      }
      #pragma unroll
      for (int mi=0;mi<4;++mi)
        #pragma unroll
        for (int ni=0;ni<4;++ni)
          acc[mi][ni] = mfma16(af[mi], bf_[ni], acc[mi][ni]);
    }
  }
  #pragma unroll
  for (int mi=0;mi<4;++mi)
    #pragma unroll
    for (int ni=0;ni<4;++ni){
      const int col = n0 + wc*64 + ni*16 + r16;
      #pragma unroll
      for (int i=0;i<4;++i){
        const int row = m0 + wr*64 + mi*16 + g*4 + i;
        float v = acc[mi][ni][i];
        if (EPI == 0){
          ((u16*)Cout)[(size_t)row*N + col] = f2bf(v);
        } else if (EPI == 1){
          float x = v + bias[col];
          x = 0.5f * x * (1.0f + erff(x * 0.70710678118f));
          ((u16*)Cout)[(size_t)row*N + col] = f2bf(x);
        } else {
          ((float*)Cout)[(size_t)row*N + col] = v;
        }
      }
    }
}

// ---------------- beta = sigmoid(hs@Wb), floor = 0.2*sigmoid(hs@Wfl + b) ----------------
__global__ __launch_bounds__(256) void beta_floor_k(
    const float* __restrict__ hs, const float* __restrict__ Wb, const float* __restrict__ Wfl,
    const float* __restrict__ flb, float* __restrict__ beta, float* __restrict__ flo)
{
  __shared__ float red[16][17];
  const int t = threadIdx.x, j = t & 15, p = t >> 4;
  const float* W = (j < 8) ? Wb : Wfl; const int jc = j & 7;
  for (int rr = 0; rr < 8; ++rr){
    const int row = blockIdx.x*8 + rr;
    const float* h = hs + (size_t)row*1024;
    float acc = 0.f;
    for (int k = p*64; k < p*64+64; ++k) acc += h[k] * W[(size_t)k*8 + jc];
    red[p][j] = acc;
    __syncthreads();
    if (t < 16){
      float s = 0.f;
      #pragma unroll
      for (int q=0;q<16;++q) s += red[q][t];
      if (t < 8) beta[(size_t)row*8 + t] = sigm(s);
      else       flo [(size_t)row*8 + (t-8)] = 0.2f * sigm(s + flb[t-8]);
    }
    __syncthreads();
  }
}

// ---------------- causal conv(K=4) + SiLU + per-head l2norm ----------------
__global__ __launch_bounds__(256) void conv_silu_k(
    const u16* __restrict__ qraw, const u16* __restrict__ kraw, const u16* __restrict__ vraw,
    const float* __restrict__ cwq, const float* __restrict__ cwk, const float* __restrict__ cwv,
    float* __restrict__ vdir, u16* __restrict__ qn, u16* __restrict__ kn)
{
  const int row = blockIdx.x;                 // b*2048 + l
  const int b = row >> 11, l = row & 2047;
  const int t = threadIdx.x, c0 = t * 4;
  float qa[4] = {0,0,0,0}, ka[4] = {0,0,0,0}, va[4] = {0,0,0,0};
  float wq[16], wk[16], wv[16];
  #pragma unroll
  for (int cc=0; cc<4; ++cc){
    float4 a = *(const float4*)(cwq + (size_t)(c0+cc)*4);
    wq[cc*4+0]=a.x; wq[cc*4+1]=a.y; wq[cc*4+2]=a.z; wq[cc*4+3]=a.w;
    float4 bq = *(const float4*)(cwk + (size_t)(c0+cc)*4);
    wk[cc*4+0]=bq.x; wk[cc*4+1]=bq.y; wk[cc*4+2]=bq.z; wk[cc*4+3]=bq.w;
    float4 c = *(const float4*)(cwv + (size_t)(c0+cc)*4);
    wv[cc*4+0]=c.x; wv[cc*4+1]=c.y; wv[cc*4+2]=c.z; wv[cc*4+3]=c.w;
  }
  #pragma unroll
  for (int i=0;i<4;++i){
    const int ls = l - 3 + i;
    if (ls < 0) continue;
    const size_t base = ((size_t)(b << 11) + ls)*1024 + c0;
    union{ ushort4 v; u16 s[4]; } xq, xk, xv;
    xq.v = *(const ushort4*)(qraw + base);
    xk.v = *(const ushort4*)(kraw + base);
    xv.v = *(const ushort4*)(vraw + base);
    #pragma unroll
    for (int cc=0; cc<4; ++cc){
      qa[cc] += bf2f(xq.s[cc]) * wq[cc*4+i];
      ka[cc] += bf2f(xk.s[cc]) * wk[cc*4+i];
      va[cc] += bf2f(xv.s[cc]) * wv[cc*4+i];
    }
  }
  #pragma unroll
  for (int cc=0; cc<4; ++cc){
    qa[cc] = qa[cc]*sigm(qa[cc]); ka[cc] = ka[cc]*sigm(ka[cc]); va[cc] = va[cc]*sigm(va[cc]);
  }
  *(float4*)(vdir + (size_t)row*1024 + c0) = make_float4(va[0],va[1],va[2],va[3]);
  float ssq = 0.f, ssk = 0.f;
  #pragma unroll
  for (int cc=0; cc<4; ++cc){ ssq += qa[cc]*qa[cc]; ssk += ka[cc]*ka[cc]; }
  #pragma unroll
  for (int m=1; m<32; m<<=1){ ssq += __shfl_xor(ssq, m, 64); ssk += __shfl_xor(ssk, m, 64); }
  const float rq = rsqrtf(ssq + 1e-6f), rk = rsqrtf(ssk + 1e-6f);
  const int head = c0 >> 7, d0 = c0 & 127;
  const size_t ob = (((size_t)(b*8 + head))*2048 + l)*128 + d0;
  ushort4 oq, ok;
  oq.x=f2bf(qa[0]*rq); oq.y=f2bf(qa[1]*rq); oq.z=f2bf(qa[2]*rq); oq.w=f2bf(qa[3]*rq);
  ok.x=f2bf(ka[0]*rk); ok.y=f2bf(ka[1]*rk); ok.z=f2bf(ka[2]*rk); ok.w=f2bf(ka[3]*rk);
  *(ushort4*)(qn + ob) = oq;
  *(ushort4*)(kn + ob) = ok;
}

// ---------------- fus2: [8192][2048]bf16 @ [2048][32]f32 + b2 ----------------
__global__ __launch_bounds__(256) void fus2_k(
    const u16* __restrict__ A, const float* __restrict__ W2, const float* __restrict__ b2,
    float* __restrict__ out)
{
  __shared__ float red[8][33];
  const int t = threadIdx.x, j = t & 31, p = t >> 5;
  for (int rr = 0; rr < 8; ++rr){
    const int row = blockIdx.x*8 + rr;
    const u16* a = A + (size_t)row*2048;
    float acc = 0.f;
    for (int k = p*256; k < p*256+256; ++k) acc += bf2f(a[k]) * W2[(size_t)k*32 + j];
    red[p][j] = acc;
    __syncthreads();
    if (t < 32){
      float s = 0.f;
      #pragma unroll
      for (int q=0;q<8;++q) s += red[q][t];
      out[(size_t)row*32 + t] = s + b2[t];
    }
    __syncthreads();
  }
}

// ---------------- UT transform per (b,h,chunk): T=(I-M)^-1, u=T@vb, w=T@kb ----------------
// Also packs operands into exact MFMA fragment layouts for the scan.
__global__ __launch_bounds__(256) void ut_k(
    const u16* __restrict__ qn, const u16* __restrict__ kn,
    const float* __restrict__ vdir, const float* __restrict__ beta,
    u16* __restrict__ alocp, float* __restrict__ updk,
    u16* __restrict__ wpk, u16* __restrict__ knpk)
{
  __shared__ __align__(16) char smem[50432];
  u16*  q_s = (u16*)smem;              // [32][128] swizzled (G-phase only)
  u16*  k_s = (u16*)(smem + 8192);     // [32][128] swizzled (G-phase only)
  float* Gm = (float*)(smem + 16384);  // [32][33] (G-phase -> inversion)
  float* wl = (float*)smem;            // [32][132] u/w-phase; aliases q_s/k_s/Gm (dead)
  float* Tm = (float*)(smem + 20608);  // [32][36]
  float* al = (float*)(smem + 25216);  // [32][36]
  u16*  knT = (u16*)(smem + 29824);    // [128][40]
  u16*  vbT = (u16*)(smem + 40064);    // [128][40] (v*beta transposed)
  float* bet = (float*)(smem + 50304); // [32]

  const int blk = blockIdx.x;
  const int ic = blk & 63, bh = blk >> 6;
  const int b = bh >> 3, h = bh & 7;
  const int l0 = ic * 32;
  const int t = threadIdx.x;
  const int lane = t & 63, w = t >> 6;
  const int g = lane >> 4, r = lane & 15;

  { // stage q,k (swizzled), knT, vbT, betas
    const int row = t >> 3, sseg = t & 7;
    const size_t gb = ((size_t)bh*2048 + l0 + row)*128;
    #pragma unroll
    for (int ss=0; ss<2; ++ss){
      const int s = sseg + ss*8;
      union{ int4 v; u16 u[8]; } kv, qv;
      kv.v = *(const int4*)(kn + gb + s*8);
      qv.v = *(const int4*)(qn + gb + s*8);
      *(int4*)((char*)k_s + row*256 + ((s ^ (row&7))*16)) = kv.v;
      *(int4*)((char*)q_s + row*256 + ((s ^ (row&7))*16)) = qv.v;
      #pragma unroll
      for (int i=0;i<8;++i) knT[(s*8+i)*40 + row] = kv.u[i];
    }
    const float betr = beta[((size_t)b*2048 + l0 + row)*8 + h];
    if (t < 32) bet[t] = beta[((size_t)b*2048 + l0 + t)*8 + h];
    const float* vp = vdir + ((size_t)b*2048 + l0 + row)*1024 + h*128 + sseg*16;
    #pragma unroll
    for (int jj=0; jj<4; ++jj){
      float4 vv = *(const float4*)(vp + jj*4);
      const int d0 = sseg*16 + jj*4;
      vbT[(d0+0)*40 + row] = f2bf(vv.x * betr);
      vbT[(d0+1)*40 + row] = f2bf(vv.y * betr);
      vbT[(d0+2)*40 + row] = f2bf(vv.z * betr);
      vbT[(d0+3)*40 + row] = f2bf(vv.w * betr);
    }
  }
  __syncthreads();

  { // G = kn@kn^T, Aloc = tril(qn@kn^T) via MFMA; wave -> (mt,nt) quadrant
    const int mt = w >> 1, nt = w & 1;
    f32x4 gacc = {0,0,0,0}, aacc = {0,0,0,0};
    #pragma unroll
    for (int kt=0; kt<4; ++kt){
      const int brow = nt*16 + r, arow = mt*16 + r;
      s16x8 bfrag = *(const s16x8*)((const char*)k_s + brow*256 + (((kt*4+g) ^ (brow&7))*16));
      s16x8 afk   = *(const s16x8*)((const char*)k_s + arow*256 + (((kt*4+g) ^ (arow&7))*16));
      s16x8 afq   = *(const s16x8*)((const char*)q_s + arow*256 + (((kt*4+g) ^ (arow&7))*16));
      gacc = mfma16(afk, bfrag, gacc);
      aacc = mfma16(afq, bfrag, aacc);
    }
    #pragma unroll
    for (int i=0;i<4;++i){
      const int rr = mt*16 + g*4 + i, cc = nt*16 + r;
      Gm[rr*33 + cc] = gacc[i];
      al[rr*36 + cc] = (cc <= rr) ? aacc[i] : 0.f;
    }
  }
  __syncthreads();

  if (w == 0){ // forward-substitution inverse, columns in lanes (lanes>=32 mirror)
    const int kk = lane & 31;
    float tc[32];
    #pragma unroll
    for (int j=0;j<32;++j) tc[j] = (j > kk) ? (-bet[j] * Gm[j*33 + kk]) : 0.f;
    #pragma unroll
    for (int i=1;i<32;++i){
      float upd = 0.f;
      #pragma unroll
      for (int j=0;j<i;++j) upd += __shfl(tc[i], j, 64) * tc[j];
      if (kk < i) tc[i] += upd;
    }
    #pragma unroll
    for (int j=0;j<32;++j) if (j == kk) tc[j] += 1.f;
    if (lane < 32){
      #pragma unroll
      for (int j=0;j<32;++j) Tm[j*36 + lane] = tc[j];
    }
  } else if (w == 1){ // pack Aloc A-frags (bf16)
    #pragma unroll
    for (int mt=0; mt<2; ++mt){
      float4 z0 = *(const float4*)(al + (mt*16+r)*36 + g*8);
      float4 z1 = *(const float4*)(al + (mt*16+r)*36 + g*8 + 4);
      *(s16x8*)(alocp + (((size_t)blk*2 + mt)*64 + lane)*8) = pack8(z0, z1);
    }
  } else { // w==2,3: pack kn^T A-frags for the S-update
    #pragma unroll
    for (int q2=0; q2<4; ++q2){
      const int mtd = (w-2)*4 + q2;
      s16x8 vv = *(const s16x8*)(knT + (mtd*16+r)*40 + g*8);
      *(s16x8*)(knpk + (((size_t)blk*8 + mtd)*64 + lane)*8) = vv;
    }
  }
  __syncthreads();

  { // u = T@vb (stored in D-frag layout), w = T@kb (row-major via wl, then packed)
    float bb[8];
    #pragma unroll
    for (int i=0;i<8;++i) bb[i] = bet[g*8+i];
    s16x8 tA[2];
    #pragma unroll
    for (int mt=0; mt<2; ++mt){
      float4 x0 = *(const float4*)(Tm + (mt*16+r)*36 + g*8);
      float4 x1 = *(const float4*)(Tm + (mt*16+r)*36 + g*8 + 4);
      tA[mt] = pack8(x0, x1);
    }
    #pragma unroll
    for (int q2=0; q2<2; ++q2){
      const int nt = w*2 + q2;
      s16x8 bu   = *(const s16x8*)(vbT + (nt*16+r)*40 + g*8);
      s16x8 braw = *(const s16x8*)(knT + (nt*16+r)*40 + g*8);
      s16x8 bw;
      #pragma unroll
      for (int i=0;i<8;++i) bw[i] = (short)f2bf(bf2f((u16)braw[i]) * bb[i]);
      #pragma unroll
      for (int mt=0; mt<2; ++mt){
        f32x4 zz = {0,0,0,0};
        f32x4 du = mfma16(tA[mt], bu, zz);
        f32x4 dw = mfma16(tA[mt], bw, zz);
        *(f32x4*)(updk + ((((size_t)blk*8 + nt)*2 + mt)*64 + lane)*4) = du;
        #pragma unroll
        for (int i=0;i<4;++i) wl[(mt*16 + g*4 + i)*132 + nt*16 + r] = dw[i];
      }
    }
  }
  __syncthreads();

  { // pack w A-frags
    #pragma unroll
    for (int q2=0; q2<2; ++q2){
      const int combo = w*2 + q2, mt = combo >> 2, kt = combo & 3;
      float4 y0 = *(const float4*)(wl + (mt*16+r)*132 + kt*32 + g*8);
      float4 y1 = *(const float4*)(wl + (mt*16+r)*132 + kt*32 + g*8 + 4);
      *(s16x8*)(wpk + ((((size_t)blk*2 + mt)*4 + kt)*64 + lane)*8) = pack8(y0, y1);
    }
  }
}

// ---------------- chunk-serial scan, 1 wave per (b,h,dv-16 slice) ----------------
__global__ __launch_bounds__(64) void scan_k(
    const u16* __restrict__ qn, const u16* __restrict__ wpk,
    const float* __restrict__ updk, const u16* __restrict__ alocp,
    const u16* __restrict__ knpk, float* __restrict__ delta)
{
  __shared__ float S[16*132];   // S^T slice: [dv_local 16][dk 128 (+pad)]
  __shared__ float UN[32*17];   // u_new roundtrip (D-frag -> B-frag relayout)
  const int blk = blockIdx.x;
  const int sl = blk & 7, bh = blk >> 3;
  const int lane = threadIdx.x;
  const int g = lane >> 4, r = lane & 15;
  for (int i = lane; i < 16*132; i += 64) S[i] = 0.f;
  for (int ic = 0; ic < 64; ++ic){
    const size_t cblk = (size_t)bh*64 + ic;
    const float* up = updk + ((cblk*8 + sl)*2)*256;
    f32x4 acc0 = -*(const f32x4*)(up + lane*4);        // acc = w@S - u = -u_new
    f32x4 acc1 = -*(const f32x4*)(up + 256 + lane*4);
    f32x4 o0 = {0,0,0,0}, o1 = {0,0,0,0};
    const u16* wbase = wpk + cblk*4096;
    const u16* qbase = qn + ((size_t)bh*2048 + ic*32)*128;
    #pragma unroll
    for (int kt=0; kt<4; ++kt){
      float4 s0 = *(const float4*)(S + r*132 + kt*32 + g*8);
      float4 s1 = *(const float4*)(S + r*132 + kt*32 + g*8 + 4);
      s16x8 sf = pack8(s0, s1);
      s16x8 w0 = *(const s16x8*)(wbase + ((size_t)(0*4 + kt)*64 + lane)*8);
      s16x8 w1 = *(const s16x8*)(wbase + ((size_t)(1*4 + kt)*64 + lane)*8);
      s16x8 q0 = *(const s16x8*)(qbase + (size_t)r*128 + kt*32 + g*8);
      s16x8 q1 = *(const s16x8*)(qbase + (size_t)(16 + r)*128 + kt*32 + g*8);
      acc0 = mfma16(w0, sf, acc0);
      acc1 = mfma16(w1, sf, acc1);
      o0 = mfma16(q0, sf, o0);
      o1 = mfma16(q1, sf, o1);
    }
    #pragma unroll
    for (int i=0;i<4;++i){
      UN[(g*4+i)*17 + r]      = -acc0[i];
      UN[(16+g*4+i)*17 + r]   = -acc1[i];
    }
    s16x8 uf;
    #pragma unroll
    for (int i=0;i<8;++i) uf[i] = (short)f2bf(UN[(g*8+i)*17 + r]);
    s16x8 a0 = *(const s16x8*)(alocp + ((cblk*2 + 0)*64 + lane)*8);
    s16x8 a1 = *(const s16x8*)(alocp + ((cblk*2 + 1)*64 + lane)*8);
    o0 = mfma16(a0, uf, o0);
    o1 = mfma16(a1, uf, o1);
    float* dbase = delta + ((size_t)bh*2048 + ic*32)*128 + sl*16 + r;
    #pragma unroll
    for (int i=0;i<4;++i){
      dbase[(size_t)(g*4+i)*128]    = o0[i];
      dbase[(size_t)(16+g*4+i)*128] = o1[i];
    }
    #pragma unroll
    for (int mtd=0; mtd<8; ++mtd){
      s16x8 ka = *(const s16x8*)(knpk + ((cblk*8 + mtd)*64 + lane)*8);
      f32x4 zz = {0,0,0,0};
      f32x4 ds = mfma16(ka, uf, zz);
      #pragma unroll
      for (int i=0;i<4;++i) S[r*132 + mtd*16 + g*4 + i] += ds[i];
    }
  }
}

// ---------------- FIR(3,31) + gating + double RMS -> o_final bf16 ----------------
__global__ __launch_bounds__(256) void fuse_k(
    const float* __restrict__ vdir, const float* __restrict__ delta,
    const float* __restrict__ fusv, const float* __restrict__ flo,
    const float* __restrict__ fsw, const float* __restrict__ flw,
    const float* __restrict__ wpf, const float* __restrict__ wno,
    u16* __restrict__ ofin)
{
  __shared__ float vt[94][128];
  __shared__ float fl_s[128*31];
  const int blk = blockIdx.x;
  const int lt = blk & 31, h = (blk >> 5) & 7, b = blk >> 8;
  const int l0 = lt * 64;
  const int t = threadIdx.x;
  for (int i = t; i < 128*31; i += 256) fl_s[i] = flw[(size_t)h*128*31 + i];
  for (int s = t; s < 94*32; s += 256){
    const int rr = s >> 5, cc = (s & 31) * 4;
    const int ls = l0 - 30 + rr;
    float4 v = {0,0,0,0};
    if (ls >= 0) v = *(const float4*)(vdir + ((size_t)b*2048 + ls)*1024 + h*128 + cc);
    *(float4*)&vt[rr][cc] = v;
  }
  __syncthreads();
  const int w = t >> 6, lane = t & 63;
  const int d0 = lane * 2;
  const float wp0 = wpf[d0], wp1 = wpf[d0+1];
  const float wn0 = wno[d0], wn1 = wno[d0+1];
  float fs0[3], fs1[3];
  #pragma unroll
  for (int i=0;i<3;++i){
    fs0[i] = fsw[((size_t)h*128 + d0)*3 + i];
    fs1[i] = fsw[((size_t)h*128 + d0 + 1)*3 + i];
  }
  for (int it = 0; it < 16; ++it){
    const int lr = it*4 + w;
    const int l = l0 + lr;
    const float* fr = fusv + ((size_t)b*2048 + l)*32 + h*4;
    const float f0=fr[0], f1=fr[1], f2=fr[2], f3=fr[3];
    const float flv = flo[((size_t)b*2048 + l)*8 + h];
    const float p = sigm(f3) * (1.f - flv);
    const float mx = fmaxf(f0, fmaxf(f1, f2));
    const float e0 = expf(f0-mx), e1 = expf(f1-mx), e2 = expf(f2-mx);
    const float inv = (1.f - p) / (e0 + e1 + e2);
    const float c0 = e0*inv, c1 = e1*inv, c2 = e2*inv;
    float sh0=0, sh1=0, lg0=0, lg1=0;
    #pragma unroll
    for (int i=0;i<31;++i){
      float2 x = *(const float2*)&vt[lr + i][d0];
      lg0 += x.x * fl_s[d0*31 + i];
      lg1 += x.y * fl_s[(d0+1)*31 + i];
    }
    #pragma unroll
    for (int i=0;i<3;++i){
      float2 x = *(const float2*)&vt[lr + 28 + i][d0];
      sh0 += x.x * fs0[i];
      sh1 += x.y * fs1[i];
    }
    float2 dl = *(const float2*)(delta + (((size_t)(b*8 + h))*2048 + l)*128 + d0);
    float2 vc = *(const float2*)&vt[lr + 30][d0];
    float o0 = c0*sh0 + c1*lg0 + c2*dl.x + p*vc.x;
    float o1 = c0*sh1 + c1*lg1 + c2*dl.y + p*vc.y;
    float ss = o0*o0 + o1*o1;
    #pragma unroll
    for (int m=1; m<64; m<<=1) ss += __shfl_xor(ss, m, 64);
    const float r1 = rsqrtf(ss * (1.f/128.f) + 1e-5f);
    const float a0 = o0*r1*wp0, a1 = o1*r1*wp1;
    float s2 = a0*a0 + a1*a1;
    #pragma unroll
    for (int m=1; m<64; m<<=1) s2 += __shfl_xor(s2, m, 64);
    const float r2 = rsqrtf(s2 * (1.f/128.f) + 1e-5f);
    const u32 h0 = f2bf(a0*r2*wn0), h1 = f2bf(a1*r2*wn1);
    *(u32*)(ofin + ((size_t)b*2048 + l)*1024 + h*128 + d0) = h0 | (h1 << 16);
  }
}

// ---------------- workspace layout (lifetime-aliased, 203 MB) ----------------
constexpr size_t OFF_HSB  = 0;
constexpr size_t OFF_WQT  = 16777216;
constexpr size_t OFF_WKT  = 18874368;
constexpr size_t OFF_WVT  = 20971520;
constexpr size_t OFF_W1T  = 23068672;
constexpr size_t OFF_WOT  = 27262976;
constexpr size_t OFF_QRAW = 29360128;   // after conv: fus1g (33.5MB spans QRAW+KRAW); after fus2: delta
constexpr size_t OFF_KRAW = 46137344;
constexpr size_t OFF_VRAW = 62914560;   // after conv: wpk
constexpr size_t OFF_FUSV = 79691776;
constexpr size_t OFF_BETA = 80740352;
constexpr size_t OFF_FLO  = 81002496;
constexpr size_t OFF_VDIR = 81264640;
constexpr size_t OFF_QN   = 114819072;
constexpr size_t OFF_KN   = 131596288;
constexpr size_t OFF_ALOC = 148373504;
constexpr size_t OFF_UPDK = 152567808;  // after scan: ofin
constexpr size_t OFF_KNPK = 186122240;  // end: 202899456

extern "C" void kernel_launch(void* const* d_in, const int* in_sizes, int n_in,
                              void* d_out, int out_size, void* d_ws, size_t ws_size,
                              hipStream_t stream)
{
  const float* hs   = (const float*)d_in[0];
  const float* Wq   = (const float*)d_in[1];
  const float* Wk   = (const float*)d_in[2];
  const float* Wv   = (const float*)d_in[3];
  const float* Wb   = (const float*)d_in[4];
  const float* cq   = (const float*)d_in[5];
  const float* ck   = (const float*)d_in[6];
  const float* cv   = (const float*)d_in[7];
  const float* firs = (const float*)d_in[8];
  const float* firl = (const float*)d_in[9];
  const float* flW  = (const float*)d_in[10];
  const float* flb  = (const float*)d_in[11];
  const float* W1   = (const float*)d_in[12];
  const float* b1   = (const float*)d_in[13];
  const float* W2   = (const float*)d_in[14];
  const float* b2   = (const float*)d_in[15];
  const float* npf  = (const float*)d_in[16];
  const float* now  = (const float*)d_in[17];
  const float* Wo   = (const float*)d_in[18];

  char* ws = (char*)d_ws;
  u16*   hsb   = (u16*)(ws + OFF_HSB);
  u16*   wqT   = (u16*)(ws + OFF_WQT);
  u16*   wkT   = (u16*)(ws + OFF_WKT);
  u16*   wvT   = (u16*)(ws + OFF_WVT);
  u16*   w1T   = (u16*)(ws + OFF_W1T);
  u16*   woT   = (u16*)(ws + OFF_WOT);
  u16*   qraw  = (u16*)(ws + OFF_QRAW);
  u16*   kraw  = (u16*)(ws + OFF_KRAW);
  u16*   vraw  = (u16*)(ws + OFF_VRAW);
  u16*   fus1g = (u16*)(ws + OFF_QRAW);   // alias (qraw/kraw dead after conv)
  float* fusv  = (float*)(ws + OFF_FUSV);
  float* beta  = (float*)(ws + OFF_BETA);
  float* flo   = (float*)(ws + OFF_FLO);
  float* vdir  = (float*)(ws + OFF_VDIR);
  u16*   qn    = (u16*)(ws + OFF_QN);
  u16*   kn    = (u16*)(ws + OFF_KN);
  u16*   alocp = (u16*)(ws + OFF_ALOC);
  float* updk  = (float*)(ws + OFF_UPDK);
  u16*   wpk   = (u16*)(ws + OFF_VRAW);   // alias (vraw dead after conv)
  u16*   knpk  = (u16*)(ws + OFF_KNPK);
  float* delta = (float*)(ws + OFF_QRAW); // alias (fus1g dead after fus2)
  u16*   ofin  = (u16*)(ws + OFF_UPDK);   // alias (updk dead after scan)

  // 1. hs -> bf16
  cvt_bf16_k<<<8192, 256, 0, stream>>>(hs, hsb, 2097152);
  // 2. weight transposes (fp32 [K][N] -> bf16 [N][K])
  transpose_bf16_k<<<dim3(32,32), 256, 0, stream>>>(Wq, wqT, 1024, 1024);
  transpose_bf16_k<<<dim3(32,32), 256, 0, stream>>>(Wk, wkT, 1024, 1024);
  transpose_bf16_k<<<dim3(32,32), 256, 0, stream>>>(Wv, wvT, 1024, 1024);
  transpose_bf16_k<<<dim3(64,32), 256, 0, stream>>>(W1, w1T, 1024, 2048);
  transpose_bf16_k<<<dim3(32,32), 256, 0, stream>>>(Wo, woT, 1024, 1024);
  // 3. beta / floor
  beta_floor_k<<<1024, 256, 0, stream>>>(hs, Wb, flW, flb, beta, flo);
  // 4. projections
  gemm_bt<0><<<dim3(8,64), 256, 0, stream>>>(hsb, wqT, qraw, nullptr, 8192, 1024, 1024);
  gemm_bt<0><<<dim3(8,64), 256, 0, stream>>>(hsb, wkT, kraw, nullptr, 8192, 1024, 1024);
  gemm_bt<0><<<dim3(8,64), 256, 0, stream>>>(hsb, wvT, vraw, nullptr, 8192, 1024, 1024);
  // 5. conv + silu + l2norm
  conv_silu_k<<<8192, 256, 0, stream>>>(qraw, kraw, vraw, cq, ck, cv, vdir, qn, kn);
  // 6. fusion MLP layer 1 (+bias, gelu)
  gemm_bt<1><<<dim3(16,64), 256, 0, stream>>>(hsb, w1T, fus1g, b1, 8192, 2048, 1024);
  // 7. fusion MLP layer 2
  fus2_k<<<1024, 256, 0, stream>>>(fus1g, W2, b2, fusv);
  // 8. UT transform + fragment packing
  ut_k<<<2048, 256, 0, stream>>>(qn, kn, vdir, beta, alocp, updk, wpk, knpk);
  // 9. chunk-serial scan
  scan_k<<<256, 64, 0, stream>>>(qn, wpk, updk, alocp, knpk, delta);
  // 10. FIR + gating + double RMS
  fuse_k<<<1024, 256, 0, stream>>>(vdir, delta, fusv, flo, firs, firl, npf, now, ofin);
  // 11. output projection
  gemm_bt<2><<<dim3(8,64), 256, 0, stream>>>(ofin, woT, d_out, nullptr, 8192, 1024, 1024);
}

// Round 2
// 655.248 us; speedup vs baseline: 2.0381x; 2.0381x over previous
//
// DeltaNet forward, MI355X/gfx950. Round 2: latency-hidden scan (reg-resident S,
// double-buffered operand prefetch, XCD co-location) + global_load_lds GEMM staging.
#include <hip/hip_runtime.h>
#include <hip/hip_bf16.h>
#include <cstdint>
#include <cstddef>

#define DEVI static __device__ __forceinline__

typedef __attribute__((ext_vector_type(4))) float f32x4;
typedef __attribute__((ext_vector_type(8))) short s16x8;
typedef unsigned short u16;
typedef unsigned int u32;

DEVI float bf2f(u16 u){ u32 x = ((u32)u) << 16; float f; __builtin_memcpy(&f, &x, 4); return f; }
DEVI u16 f2bf(float f){ u32 x; __builtin_memcpy(&x, &f, 4); u32 r = x + 0x7fffu + ((x >> 16) & 1u); return (u16)(r >> 16); }
DEVI float sigm(float x){ return 1.0f / (1.0f + expf(-x)); }
DEVI f32x4 mfma16(s16x8 a, s16x8 b, f32x4 c){ return __builtin_amdgcn_mfma_f32_16x16x32_bf16(a, b, c, 0, 0, 0); }
DEVI s16x8 pack8(float4 a, float4 b){
  s16x8 v;
  v[0]=(short)f2bf(a.x); v[1]=(short)f2bf(a.y); v[2]=(short)f2bf(a.z); v[3]=(short)f2bf(a.w);
  v[4]=(short)f2bf(b.x); v[5]=(short)f2bf(b.y); v[6]=(short)f2bf(b.z); v[7]=(short)f2bf(b.w);
  return v;
}

// async global->LDS, 16B per lane; LDS dest is wave-uniform base + lane*16.
#define GLL16(gp, lp) __builtin_amdgcn_global_load_lds( \
    (const __attribute__((address_space(1))) void*)(gp), \
    (__attribute__((address_space(3))) void*)(lp), 16, 0, 0)

// ---------------- convert fp32 -> bf16 (vectorized) ----------------
__global__ __launch_bounds__(256) void cvt_bf16_k(const float* __restrict__ src, u16* __restrict__ dst, int n4){
  int i = blockIdx.x * 256 + threadIdx.x;
  if (i < n4){
    float4 v = ((const float4*)src)[i];
    ushort4 o; o.x = f2bf(v.x); o.y = f2bf(v.y); o.z = f2bf(v.z); o.w = f2bf(v.w);
    ((ushort4*)dst)[i] = o;
  }
}

// ---------------- transpose fp32 [K][N] -> bf16 [N][K] ----------------
__global__ __launch_bounds__(256) void transpose_bf16_k(const float* __restrict__ src, u16* __restrict__ dst, int K, int N){
  __shared__ float tile[32][33];
  const int n0 = blockIdx.x * 32, k0 = blockIdx.y * 32;
  const int t = threadIdx.x, cc = t & 31, rb = t >> 5;
  #pragma unroll
  for (int it = 0; it < 4; ++it){ int rr = rb + it*8; tile[rr][cc] = src[(size_t)(k0+rr)*N + n0 + cc]; }
  __syncthreads();
  #pragma unroll
  for (int it = 0; it < 4; ++it){ int rr = rb + it*8; dst[(size_t)(n0+rr)*K + k0 + cc] = f2bf(tile[cc][rr]); }
}

// ---------------- GEMM: A[M][K]bf16 @ Bt[N][K]bf16 -> C[M][N] ----------------
// 128x128 tile, BK=64, 4 waves (2x2), 4x4 16x16 frags/wave.
// m97 structure: global_load_lds width-16 staging, linear LDS, 2 barriers/K-step.
// EPI: 0 = store bf16, 1 = +bias, exact gelu, store bf16, 2 = store fp32.
template<int EPI>
__global__ __launch_bounds__(256, 2) void gemm_bt(
    const u16* __restrict__ A, const u16* __restrict__ Bt, void* __restrict__ Cout,
    const float* __restrict__ bias, int M, int N, int K)
{
  __shared__ __align__(16) u16 As[128*64];
  __shared__ __align__(16) u16 Bs[128*64];
  const int t = threadIdx.x;
  const int lane = t & 63, w = t >> 6;
  const int wr = w >> 1, wc = w & 1;
  const int g = lane >> 4, r16 = lane & 15;
  const int m0 = blockIdx.y * 128, n0 = blockIdx.x * 128;
  f32x4 acc[4][4];
  #pragma unroll
  for (int i=0;i<4;++i){ f32x4 z = {0,0,0,0}; acc[i][0]=z; acc[i][1]=z; acc[i][2]=z; acc[i][3]=z; }
  const int NK = K / 64;
  const int slot_l = w*64 + lane;           // per-j offset j*256 added below
  for (int kt = 0; kt < NK; ++kt){
    __syncthreads();                        // previous tile fully consumed
    #pragma unroll
    for (int j=0;j<4;++j){
      const int sl = j*256 + slot_l;
      const int row = sl >> 3, ch = sl & 7;
      GLL16(A  + (size_t)(m0+row)*K + kt*64 + ch*8, As + (size_t)(j*256 + w*64)*8);
      GLL16(Bt + (size_t)(n0+row)*K + kt*64 + ch*8, Bs + (size_t)(j*256 + w*64)*8);
    }
    __syncthreads();                        // vmcnt(0) drained -> tile visible
    #pragma unroll
    for (int kh = 0; kh < 2; ++kh){
      s16x8 af[4], bf_[4];
      #pragma unroll
      for (int i=0;i<4;++i){
        const int arow = wr*64 + i*16 + r16;
        af[i]  = *(const s16x8*)(As + (size_t)arow*64 + (4*kh+g)*8);
        const int brow = wc*64 + i*16 + r16;
        bf_[i] = *(const s16x8*)(Bs + (size_t)brow*64 + (4*kh+g)*8);
      }
      #pragma unroll
      for (int mi=0;mi<4;++mi)
        #pragma unroll
        for (int ni=0;ni<4;++ni)
          acc[mi][ni] = mfma16(af[mi], bf_[ni], acc[mi][ni]);
    }
  }
  #pragma unroll
  for (int mi=0;mi<4;++mi)
    #pragma unroll
    for (int ni=0;ni<4;++ni){
      const int col = n0 + wc*64 + ni*16 + r16;
      #pragma unroll
      for (int i=0;i<4;++i){
        const int row = m0 + wr*64 + mi*16 + g*4 + i;
        float v = acc[mi][ni][i];
        if (EPI == 0){
          ((u16*)Cout)[(size_t)row*N + col] = f2bf(v);
        } else if (EPI == 1){
          float x = v + bias[col];
          x = 0.5f * x * (1.0f + erff(x * 0.70710678118f));
          ((u16*)Cout)[(size_t)row*N + col] = f2bf(x);
        } else {
          ((float*)Cout)[(size_t)row*N + col] = v;
        }
      }
    }
}

// ---------------- beta = sigmoid(hs@Wb), floor = 0.2*sigmoid(hs@Wfl + b) ----------------
__global__ __launch_bounds__(256) void beta_floor_k(
    const float* __restrict__ hs, const float* __restrict__ Wb, const float* __restrict__ Wfl,
    const float* __restrict__ flb, float* __restrict__ beta, float* __restrict__ flo)
{
  __shared__ float red[16][17];
  const int t = threadIdx.x, j = t & 15, p = t >> 4;
  const float* W = (j < 8) ? Wb : Wfl; const int jc = j & 7;
  for (int rr = 0; rr < 8; ++rr){
    const int row = blockIdx.x*8 + rr;
    const float* h = hs + (size_t)row*1024;
    float acc = 0.f;
    for (int k = p*64; k < p*64+64; ++k) acc += h[k] * W[(size_t)k*8 + jc];
    red[p][j] = acc;
    __syncthreads();
    if (t < 16){
      float s = 0.f;
      #pragma unroll
      for (int q=0;q<16;++q) s += red[q][t];
      if (t < 8) beta[(size_t)row*8 + t] = sigm(s);
      else       flo [(size_t)row*8 + (t-8)] = 0.2f * sigm(s + flb[t-8]);
    }
    __syncthreads();
  }
}

// ---------------- causal conv(K=4) + SiLU + per-head l2norm ----------------
__global__ __launch_bounds__(256) void conv_silu_k(
    const u16* __restrict__ qraw, const u16* __restrict__ kraw, const u16* __restrict__ vraw,
    const float* __restrict__ cwq, const float* __restrict__ cwk, const float* __restrict__ cwv,
    float* __restrict__ vdir, u16* __restrict__ qn, u16* __restrict__ kn)
{
  const int row = blockIdx.x;                 // b*2048 + l
  const int b = row >> 11, l = row & 2047;
  const int t = threadIdx.x, c0 = t * 4;
  float qa[4] = {0,0,0,0}, ka[4] = {0,0,0,0}, va[4] = {0,0,0,0};
  float wq[16], wk[16], wv[16];
  #pragma unroll
  for (int cc=0; cc<4; ++cc){
    float4 a = *(const float4*)(cwq + (size_t)(c0+cc)*4);
    wq[cc*4+0]=a.x; wq[cc*4+1]=a.y; wq[cc*4+2]=a.z; wq[cc*4+3]=a.w;
    float4 bq = *(const float4*)(cwk + (size_t)(c0+cc)*4);
    wk[cc*4+0]=bq.x; wk[cc*4+1]=bq.y; wk[cc*4+2]=bq.z; wk[cc*4+3]=bq.w;
    float4 c = *(const float4*)(cwv + (size_t)(c0+cc)*4);
    wv[cc*4+0]=c.x; wv[cc*4+1]=c.y; wv[cc*4+2]=c.z; wv[cc*4+3]=c.w;
  }
  #pragma unroll
  for (int i=0;i<4;++i){
    const int ls = l - 3 + i;
    if (ls < 0) continue;
    const size_t base = ((size_t)(b << 11) + ls)*1024 + c0;
    union{ ushort4 v; u16 s[4]; } xq, xk, xv;
    xq.v = *(const ushort4*)(qraw + base);
    xk.v = *(const ushort4*)(kraw + base);
    xv.v = *(const ushort4*)(vraw + base);
    #pragma unroll
    for (int cc=0; cc<4; ++cc){
      qa[cc] += bf2f(xq.s[cc]) * wq[cc*4+i];
      ka[cc] += bf2f(xk.s[cc]) * wk[cc*4+i];
      va[cc] += bf2f(xv.s[cc]) * wv[cc*4+i];
    }
  }
  #pragma unroll
  for (int cc=0; cc<4; ++cc){
    qa[cc] = qa[cc]*sigm(qa[cc]); ka[cc] = ka[cc]*sigm(ka[cc]); va[cc] = va[cc]*sigm(va[cc]);
  }
  *(float4*)(vdir + (size_t)row*1024 + c0) = make_float4(va[0],va[1],va[2],va[3]);
  float ssq = 0.f, ssk = 0.f;
  #pragma unroll
  for (int cc=0; cc<4; ++cc){ ssq += qa[cc]*qa[cc]; ssk += ka[cc]*ka[cc]; }
  #pragma unroll
  for (int m=1; m<32; m<<=1){ ssq += __shfl_xor(ssq, m, 64); ssk += __shfl_xor(ssk, m, 64); }
  const float rq = rsqrtf(ssq + 1e-6f), rk = rsqrtf(ssk + 1e-6f);
  const int head = c0 >> 7, d0 = c0 & 127;
  const size_t ob = (((size_t)(b*8 + head))*2048 + l)*128 + d0;
  ushort4 oq, ok;
  oq.x=f2bf(qa[0]*rq); oq.y=f2bf(qa[1]*rq); oq.z=f2bf(qa[2]*rq); oq.w=f2bf(qa[3]*rq);
  ok.x=f2bf(ka[0]*rk); ok.y=f2bf(ka[1]*rk); ok.z=f2bf(ka[2]*rk); ok.w=f2bf(ka[3]*rk);
  *(ushort4*)(qn + ob) = oq;
  *(ushort4*)(kn + ob) = ok;
}

// ---------------- fus2: [8192][2048]bf16 @ [2048][32]f32 + b2 ----------------
__global__ __launch_bounds__(256) void fus2_k(
    const u16* __restrict__ A, const float* __restrict__ W2, const float* __restrict__ b2,
    float* __restrict__ out)
{
  __shared__ float red[8][33];
  const int t = threadIdx.x, j = t & 31, p = t >> 5;
  for (int rr = 0; rr < 8; ++rr){
    const int row = blockIdx.x*8 + rr;
    const u16* a = A + (size_t)row*2048;
    float acc = 0.f;
    for (int k = p*256; k < p*256+256; ++k) acc += bf2f(a[k]) * W2[(size_t)k*32 + j];
    red[p][j] = acc;
    __syncthreads();
    if (t < 32){
      float s = 0.f;
      #pragma unroll
      for (int q=0;q<8;++q) s += red[q][t];
      out[(size_t)row*32 + t] = s + b2[t];
    }
    __syncthreads();
  }
}

// ---------------- UT transform per (b,h,chunk): T=(I-M)^-1, u=T@vb, w=T@kb ----------------
__global__ __launch_bounds__(256) void ut_k(
    const u16* __restrict__ qn, const u16* __restrict__ kn,
    const float* __restrict__ vdir, const float* __restrict__ beta,
    u16* __restrict__ alocp, float* __restrict__ updk,
    u16* __restrict__ wpk, u16* __restrict__ knpk)
{
  __shared__ __align__(16) char smem[50432];
  u16*  q_s = (u16*)smem;              // [32][128] swizzled (G-phase only)
  u16*  k_s = (u16*)(smem + 8192);     // [32][128] swizzled (G-phase only)
  float* Gm = (float*)(smem + 16384);  // [32][33] (G-phase -> inversion)
  float* wl = (float*)smem;            // [32][132] u/w-phase; aliases q_s/k_s/Gm (dead)
  float* Tm = (float*)(smem + 20608);  // [32][36]
  float* al = (float*)(smem + 25216);  // [32][36]
  u16*  knT = (u16*)(smem + 29824);    // [128][40]
  u16*  vbT = (u16*)(smem + 40064);    // [128][40] (v*beta transposed)
  float* bet = (float*)(smem + 50304); // [32]

  const int blk = blockIdx.x;
  const int ic = blk & 63, bh = blk >> 6;
  const int b = bh >> 3, h = bh & 7;
  const int l0 = ic * 32;
  const int t = threadIdx.x;
  const int lane = t & 63, w = t >> 6;
  const int g = lane >> 4, r = lane & 15;

  { // stage q,k (swizzled), knT, vbT, betas
    const int row = t >> 3, sseg = t & 7;
    const size_t gb = ((size_t)bh*2048 + l0 + row)*128;
    #pragma unroll
    for (int ss=0; ss<2; ++ss){
      const int s = sseg + ss*8;
      union{ int4 v; u16 u[8]; } kv, qv;
      kv.v = *(const int4*)(kn + gb + s*8);
      qv.v = *(const int4*)(qn + gb + s*8);
      *(int4*)((char*)k_s + row*256 + ((s ^ (row&7))*16)) = kv.v;
      *(int4*)((char*)q_s + row*256 + ((s ^ (row&7))*16)) = qv.v;
      #pragma unroll
      for (int i=0;i<8;++i) knT[(s*8+i)*40 + row] = kv.u[i];
    }
    const float betr = beta[((size_t)b*2048 + l0 + row)*8 + h];
    if (t < 32) bet[t] = beta[((size_t)b*2048 + l0 + t)*8 + h];
    const float* vp = vdir + ((size_t)b*2048 + l0 + row)*1024 + h*128 + sseg*16;
    #pragma unroll
    for (int jj=0; jj<4; ++jj){
      float4 vv = *(const float4*)(vp + jj*4);
      const int d0 = sseg*16 + jj*4;
      vbT[(d0+0)*40 + row] = f2bf(vv.x * betr);
      vbT[(d0+1)*40 + row] = f2bf(vv.y * betr);
      vbT[(d0+2)*40 + row] = f2bf(vv.z * betr);
      vbT[(d0+3)*40 + row] = f2bf(vv.w * betr);
    }
  }
  __syncthreads();

  { // G = kn@kn^T, Aloc = tril(qn@kn^T) via MFMA; wave -> (mt,nt) quadrant
    const int mt = w >> 1, nt = w & 1;
    f32x4 gacc = {0,0,0,0}, aacc = {0,0,0,0};
    #pragma unroll
    for (int kt=0; kt<4; ++kt){
      const int brow = nt*16 + r, arow = mt*16 + r;
      s16x8 bfrag = *(const s16x8*)((const char*)k_s + brow*256 + (((kt*4+g) ^ (brow&7))*16));
      s16x8 afk   = *(const s16x8*)((const char*)k_s + arow*256 + (((kt*4+g) ^ (arow&7))*16));
      s16x8 afq   = *(const s16x8*)((const char*)q_s + arow*256 + (((kt*4+g) ^ (arow&7))*16));
      gacc = mfma16(afk, bfrag, gacc);
      aacc = mfma16(afq, bfrag, aacc);
    }
    #pragma unroll
    for (int i=0;i<4;++i){
      const int rr = mt*16 + g*4 + i, cc = nt*16 + r;
      Gm[rr*33 + cc] = gacc[i];
      al[rr*36 + cc] = (cc <= rr) ? aacc[i] : 0.f;
    }
  }
  __syncthreads();

  if (w == 0){ // forward-substitution inverse, columns in lanes (lanes>=32 mirror)
    const int kk = lane & 31;
    float tc[32];
    #pragma unroll
    for (int j=0;j<32;++j) tc[j] = (j > kk) ? (-bet[j] * Gm[j*33 + kk]) : 0.f;
    #pragma unroll
    for (int i=1;i<32;++i){
      float upd = 0.f;
      #pragma unroll
      for (int j=0;j<i;++j) upd += __shfl(tc[i], j, 64) * tc[j];
      if (kk < i) tc[i] += upd;
    }
    #pragma unroll
    for (int j=0;j<32;++j) if (j == kk) tc[j] += 1.f;
    if (lane < 32){
      #pragma unroll
      for (int j=0;j<32;++j) Tm[j*36 + lane] = tc[j];
    }
  } else if (w == 1){ // pack Aloc A-frags (bf16)
    #pragma unroll
    for (int mt=0; mt<2; ++mt){
      float4 z0 = *(const float4*)(al + (mt*16+r)*36 + g*8);
      float4 z1 = *(const float4*)(al + (mt*16+r)*36 + g*8 + 4);
      *(s16x8*)(alocp + (((size_t)blk*2 + mt)*64 + lane)*8) = pack8(z0, z1);
    }
  } else { // w==2,3: pack kn^T A-frags for the S-update
    #pragma unroll
    for (int q2=0; q2<4; ++q2){
      const int mtd = (w-2)*4 + q2;
      s16x8 vv = *(const s16x8*)(knT + (mtd*16+r)*40 + g*8);
      *(s16x8*)(knpk + (((size_t)blk*8 + mtd)*64 + lane)*8) = vv;
    }
  }
  __syncthreads();

  { // u = T@vb (stored in D-frag layout), w = T@kb (row-major via wl, then packed)
    float bb[8];
    #pragma unroll
    for (int i=0;i<8;++i) bb[i] = bet[g*8+i];
    s16x8 tA[2];
    #pragma unroll
    for (int mt=0; mt<2; ++mt){
      float4 x0 = *(const float4*)(Tm + (mt*16+r)*36 + g*8);
      float4 x1 = *(const float4*)(Tm + (mt*16+r)*36 + g*8 + 4);
      tA[mt] = pack8(x0, x1);
    }
    #pragma unroll
    for (int q2=0; q2<2; ++q2){
      const int nt = w*2 + q2;
      s16x8 bu   = *(const s16x8*)(vbT + (nt*16+r)*40 + g*8);
      s16x8 braw = *(const s16x8*)(knT + (nt*16+r)*40 + g*8);
      s16x8 bw;
      #pragma unroll
      for (int i=0;i<8;++i) bw[i] = (short)f2bf(bf2f((u16)braw[i]) * bb[i]);
      #pragma unroll
      for (int mt=0; mt<2; ++mt){
        f32x4 zz = {0,0,0,0};
        f32x4 du = mfma16(tA[mt], bu, zz);
        f32x4 dw = mfma16(tA[mt], bw, zz);
        *(f32x4*)(updk + ((((size_t)blk*8 + nt)*2 + mt)*64 + lane)*4) = du;
        #pragma unroll
        for (int i=0;i<4;++i) wl[(mt*16 + g*4 + i)*132 + nt*16 + r] = dw[i];
      }
    }
  }
  __syncthreads();

  { // pack w A-frags
    #pragma unroll
    for (int q2=0; q2<2; ++q2){
      const int combo = w*2 + q2, mt = combo >> 2, kt = combo & 3;
      float4 y0 = *(const float4*)(wl + (mt*16+r)*132 + kt*32 + g*8);
      float4 y1 = *(const float4*)(wl + (mt*16+r)*132 + kt*32 + g*8 + 4);
      *(s16x8*)(wpk + ((((size_t)blk*2 + mt)*4 + kt)*64 + lane)*8) = pack8(y0, y1);
    }
  }
}

// ---------------- chunk-serial scan, 1 wave per (b,h,dv-16 slice) ----------------
// S lives in registers (MFMA C-accumulate); all global operands double-buffered;
// block remap sl=blk>>5, bh=blk&31 co-locates a bh's 8 slices on one XCD for L2 reuse.
struct SBuf {
  f32x4 u0, u1;       // -u init (fp32 D-frag)
  s16x8 wf[8];        // w A-frags [mt*4+kt]
  s16x8 q0[4], q1[4]; // q A-frags per kt (rows 0-15 / 16-31)
  s16x8 a0, a1;       // Aloc A-frags
  s16x8 kf[8];        // kn^T A-frags [mtd]
};

DEVI void scan_load(SBuf& b, const float* up, const u16* wp, const u16* qp,
                    const u16* ap, const u16* kp, int r, int g){
  b.u0 = *(const f32x4*)(up);
  b.u1 = *(const f32x4*)(up + 256);
  #pragma unroll
  for (int j=0;j<8;++j) b.wf[j] = *(const s16x8*)(wp + j*512);
  #pragma unroll
  for (int kt=0;kt<4;++kt){
    b.q0[kt] = *(const s16x8*)(qp + r*128 + kt*32 + g*8);
    b.q1[kt] = *(const s16x8*)(qp + (16+r)*128 + kt*32 + g*8);
  }
  b.a0 = *(const s16x8*)(ap);
  b.a1 = *(const s16x8*)(ap + 512);
  #pragma unroll
  for (int j=0;j<8;++j) b.kf[j] = *(const s16x8*)(kp + j*512);
}

DEVI void scan_step(const SBuf& b, float* SL, float* UN, f32x4* Sf,
                    float* dptr, int r, int g){
  // S^T (fp32, LDS) -> bf16 B-frags
  s16x8 sf[4];
  #pragma unroll
  for (int kt=0;kt<4;++kt){
    float4 s0 = *(const float4*)&SL[r*132 + kt*32 + g*8];
    float4 s1 = *(const float4*)&SL[r*132 + kt*32 + g*8 + 4];
    sf[kt] = pack8(s0, s1);
  }
  f32x4 acc0 = -b.u0, acc1 = -b.u1;      // acc = w@S - u = -u_new
  f32x4 o0 = {0,0,0,0}, o1 = {0,0,0,0};
  #pragma unroll
  for (int kt=0;kt<4;++kt){
    acc0 = mfma16(b.wf[kt],   sf[kt], acc0);
    acc1 = mfma16(b.wf[4+kt], sf[kt], acc1);
    o0   = mfma16(b.q0[kt],   sf[kt], o0);
    o1   = mfma16(b.q1[kt],   sf[kt], o1);
  }
  // u_new D-frag -> B-frag via small LDS roundtrip
  #pragma unroll
  for (int i=0;i<4;++i){
    UN[(g*4+i)*17 + r]    = -acc0[i];
    UN[(16+g*4+i)*17 + r] = -acc1[i];
  }
  s16x8 uf;
  #pragma unroll
  for (int i=0;i<8;++i) uf[i] = (short)f2bf(UN[(g*8+i)*17 + r]);
  o0 = mfma16(b.a0, uf, o0);
  o1 = mfma16(b.a1, uf, o1);
  #pragma unroll
  for (int i=0;i<4;++i){
    dptr[(size_t)(g*4+i)*128]    = o0[i];
    dptr[(size_t)(16+g*4+i)*128] = o1[i];
  }
  // S update fully in registers (fp32 accumulate inside MFMA)
  #pragma unroll
  for (int m=0;m<8;++m) Sf[m] = mfma16(b.kf[m], uf, Sf[m]);
  // publish S^T to LDS for next iteration's B-frag read
  #pragma unroll
  for (int m=0;m<8;++m){
    float4 w4 = make_float4(Sf[m][0], Sf[m][1], Sf[m][2], Sf[m][3]);
    *(float4*)&SL[r*132 + m*16 + g*4] = w4;
  }
}

__global__ __launch_bounds__(64, 1) void scan_k(
    const u16* __restrict__ qn, const u16* __restrict__ wpk,
    const float* __restrict__ updk, const u16* __restrict__ alocp,
    const u16* __restrict__ knpk, float* __restrict__ delta)
{
  __shared__ float SL[16*132];
  __shared__ float UN[32*17];
  const int blk = blockIdx.x;
  const int sl = blk >> 5, bh = blk & 31;   // same-bh slices -> same XCD
  const int lane = threadIdx.x;
  const int g = lane >> 4, r = lane & 15;
  for (int i = lane; i < 16*132; i += 64) SL[i] = 0.f;
  f32x4 Sf[8];
  #pragma unroll
  for (int m=0;m<8;++m){ f32x4 z = {0,0,0,0}; Sf[m] = z; }

  const float* upB = updk  + ((size_t)bh*64*8 + sl)*512 + lane*4;
  const u16*   wpB = wpk   + (size_t)bh*64*4096 + (size_t)lane*8;
  const u16*   qpB = qn    + (size_t)bh*2048*128;
  const u16*   apB = alocp + (size_t)bh*64*1024 + (size_t)lane*8;
  const u16*   kpB = knpk  + (size_t)bh*64*4096 + (size_t)lane*8;
  float*       dB  = delta + (size_t)bh*2048*128 + sl*16 + r;

  SBuf A, B;
  scan_load(A, upB, wpB, qpB, apB, kpB, r, g);
  for (int ic = 0; ic < 64; ic += 2){
    scan_load(B, upB + (size_t)(ic+1)*4096, wpB + (size_t)(ic+1)*4096,
              qpB + (size_t)(ic+1)*4096, apB + (size_t)(ic+1)*1024,
              kpB + (size_t)(ic+1)*4096, r, g);
    scan_step(A, SL, UN, Sf, dB + (size_t)ic*4096, r, g);
    if (ic + 2 < 64)
      scan_load(A, upB + (size_t)(ic+2)*4096, wpB + (size_t)(ic+2)*4096,
                qpB + (size_t)(ic+2)*4096, apB + (size_t)(ic+2)*1024,
                kpB + (size_t)(ic+2)*4096, r, g);
    scan_step(B, SL, UN, Sf, dB + (size_t)(ic+1)*4096, r, g);
  }
}

// ---------------- FIR(3,31) + gating + double RMS -> o_final bf16 ----------------
__global__ __launch_bounds__(256) void fuse_k(
    const float* __restrict__ vdir, const float* __restrict__ delta,
    const float* __restrict__ fusv, const float* __restrict__ flo,
    const float* __restrict__ fsw, const float* __restrict__ flw,
    const float* __restrict__ wpf, const float* __restrict__ wno,
    u16* __restrict__ ofin)
{
  __shared__ float vt[94][128];
  __shared__ float fl_s[128*31];
  const int blk = blockIdx.x;
  const int lt = blk & 31, h = (blk >> 5) & 7, b = blk >> 8;
  const int l0 = lt * 64;
  const int t = threadIdx.x;
  for (int i = t; i < 128*31; i += 256) fl_s[i] = flw[(size_t)h*128*31 + i];
  for (int s = t; s < 94*32; s += 256){
    const int rr = s >> 5, cc = (s & 31) * 4;
    const int ls = l0 - 30 + rr;
    float4 v = {0,0,0,0};
    if (ls >= 0) v = *(const float4*)(vdir + ((size_t)b*2048 + ls)*1024 + h*128 + cc);
    *(float4*)&vt[rr][cc] = v;
  }
  __syncthreads();
  const int w = t >> 6, lane = t & 63;
  const int d0 = lane * 2;
  const float wp0 = wpf[d0], wp1 = wpf[d0+1];
  const float wn0 = wno[d0], wn1 = wno[d0+1];
  float fs0[3], fs1[3];
  #pragma unroll
  for (int i=0;i<3;++i){
    fs0[i] = fsw[((size_t)h*128 + d0)*3 + i];
    fs1[i] = fsw[((size_t)h*128 + d0 + 1)*3 + i];
  }
  for (int it = 0; it < 16; ++it){
    const int lr = it*4 + w;
    const int l = l0 + lr;
    const float* fr = fusv + ((size_t)b*2048 + l)*32 + h*4;
    const float f0=fr[0], f1=fr[1], f2=fr[2], f3=fr[3];
    const float flv = flo[((size_t)b*2048 + l)*8 + h];
    const float p = sigm(f3) * (1.f - flv);
    const float mx = fmaxf(f0, fmaxf(f1, f2));
    const float e0 = expf(f0-mx), e1 = expf(f1-mx), e2 = expf(f2-mx);
    const float inv = (1.f - p) / (e0 + e1 + e2);
    const float c0 = e0*inv, c1 = e1*inv, c2 = e2*inv;
    float sh0=0, sh1=0, lg0=0, lg1=0;
    #pragma unroll
    for (int i=0;i<31;++i){
      float2 x = *(const float2*)&vt[lr + i][d0];
      lg0 += x.x * fl_s[d0*31 + i];
      lg1 += x.y * fl_s[(d0+1)*31 + i];
    }
    #pragma unroll
    for (int i=0;i<3;++i){
      float2 x = *(const float2*)&vt[lr + 28 + i][d0];
      sh0 += x.x * fs0[i];
      sh1 += x.y * fs1[i];
    }
    float2 dl = *(const float2*)(delta + (((size_t)(b*8 + h))*2048 + l)*128 + d0);
    float2 vc = *(const float2*)&vt[lr + 30][d0];
    float o0 = c0*sh0 + c1*lg0 + c2*dl.x + p*vc.x;
    float o1 = c0*sh1 + c1*lg1 + c2*dl.y + p*vc.y;
    float ss = o0*o0 + o1*o1;
    #pragma unroll
    for (int m=1; m<64; m<<=1) ss += __shfl_xor(ss, m, 64);
    const float r1 = rsqrtf(ss * (1.f/128.f) + 1e-5f);
    const float a0 = o0*r1*wp0, a1 = o1*r1*wp1;
    float s2 = a0*a0 + a1*a1;
    #pragma unroll
    for (int m=1; m<64; m<<=1) s2 += __shfl_xor(s2, m, 64);
    const float r2 = rsqrtf(s2 * (1.f/128.f) + 1e-5f);
    const u32 h0 = f2bf(a0*r2*wn0), h1 = f2bf(a1*r2*wn1);
    *(u32*)(ofin + ((size_t)b*2048 + l)*1024 + h*128 + d0) = h0 | (h1 << 16);
  }
}

// ---------------- workspace layout (lifetime-aliased, 203 MB) ----------------
constexpr size_t OFF_HSB  = 0;
constexpr size_t OFF_WQT  = 16777216;
constexpr size_t OFF_WKT  = 18874368;
constexpr size_t OFF_WVT  = 20971520;
constexpr size_t OFF_W1T  = 23068672;
constexpr size_t OFF_WOT  = 27262976;
constexpr size_t OFF_QRAW = 29360128;   // after conv: fus1g (33.5MB spans QRAW+KRAW); after fus2: delta
constexpr size_t OFF_KRAW = 46137344;
constexpr size_t OFF_VRAW = 62914560;   // after conv: wpk
constexpr size_t OFF_FUSV = 79691776;
constexpr size_t OFF_BETA = 80740352;
constexpr size_t OFF_FLO  = 81002496;
constexpr size_t OFF_VDIR = 81264640;
constexpr size_t OFF_QN   = 114819072;
constexpr size_t OFF_KN   = 131596288;
constexpr size_t OFF_ALOC = 148373504;
constexpr size_t OFF_UPDK = 152567808;  // after scan: ofin
constexpr size_t OFF_KNPK = 186122240;  // end: 202899456

extern "C" void kernel_launch(void* const* d_in, const int* in_sizes, int n_in,
                              void* d_out, int out_size, void* d_ws, size_t ws_size,
                              hipStream_t stream)
{
  const float* hs   = (const float*)d_in[0];
  const float* Wq   = (const float*)d_in[1];
  const float* Wk   = (const float*)d_in[2];
  const float* Wv   = (const float*)d_in[3];
  const float* Wb   = (const float*)d_in[4];
  const float* cq   = (const float*)d_in[5];
  const float* ck   = (const float*)d_in[6];
  const float* cv   = (const float*)d_in[7];
  const float* firs = (const float*)d_in[8];
  const float* firl = (const float*)d_in[9];
  const float* flW  = (const float*)d_in[10];
  const float* flb  = (const float*)d_in[11];
  const float* W1   = (const float*)d_in[12];
  const float* b1   = (const float*)d_in[13];
  const float* W2   = (const float*)d_in[14];
  const float* b2   = (const float*)d_in[15];
  const float* npf  = (const float*)d_in[16];
  const float* now  = (const float*)d_in[17];
  const float* Wo   = (const float*)d_in[18];

  char* ws = (char*)d_ws;
  u16*   hsb   = (u16*)(ws + OFF_HSB);
  u16*   wqT   = (u16*)(ws + OFF_WQT);
  u16*   wkT   = (u16*)(ws + OFF_WKT);
  u16*   wvT   = (u16*)(ws + OFF_WVT);
  u16*   w1T   = (u16*)(ws + OFF_W1T);
  u16*   woT   = (u16*)(ws + OFF_WOT);
  u16*   qraw  = (u16*)(ws + OFF_QRAW);
  u16*   kraw  = (u16*)(ws + OFF_KRAW);
  u16*   vraw  = (u16*)(ws + OFF_VRAW);
  u16*   fus1g = (u16*)(ws + OFF_QRAW);   // alias (qraw/kraw dead after conv)
  float* fusv  = (float*)(ws + OFF_FUSV);
  float* beta  = (float*)(ws + OFF_BETA);
  float* flo   = (float*)(ws + OFF_FLO);
  float* vdir  = (float*)(ws + OFF_VDIR);
  u16*   qn    = (u16*)(ws + OFF_QN);
  u16*   kn    = (u16*)(ws + OFF_KN);
  u16*   alocp = (u16*)(ws + OFF_ALOC);
  float* updk  = (float*)(ws + OFF_UPDK);
  u16*   wpk   = (u16*)(ws + OFF_VRAW);   // alias (vraw dead after conv)
  u16*   knpk  = (u16*)(ws + OFF_KNPK);
  float* delta = (float*)(ws + OFF_QRAW); // alias (fus1g dead after fus2)
  u16*   ofin  = (u16*)(ws + OFF_UPDK);   // alias (updk dead after scan)

  // 1. hs -> bf16
  cvt_bf16_k<<<8192, 256, 0, stream>>>(hs, hsb, 2097152);
  // 2. weight transposes (fp32 [K][N] -> bf16 [N][K])
  transpose_bf16_k<<<dim3(32,32), 256, 0, stream>>>(Wq, wqT, 1024, 1024);
  transpose_bf16_k<<<dim3(32,32), 256, 0, stream>>>(Wk, wkT, 1024, 1024);
  transpose_bf16_k<<<dim3(32,32), 256, 0, stream>>>(Wv, wvT, 1024, 1024);
  transpose_bf16_k<<<dim3(64,32), 256, 0, stream>>>(W1, w1T, 1024, 2048);
  transpose_bf16_k<<<dim3(32,32), 256, 0, stream>>>(Wo, woT, 1024, 1024);
  // 3. beta / floor
  beta_floor_k<<<1024, 256, 0, stream>>>(hs, Wb, flW, flb, beta, flo);
  // 4. projections
  gemm_bt<0><<<dim3(8,64), 256, 0, stream>>>(hsb, wqT, qraw, nullptr, 8192, 1024, 1024);
  gemm_bt<0><<<dim3(8,64), 256, 0, stream>>>(hsb, wkT, kraw, nullptr, 8192, 1024, 1024);
  gemm_bt<0><<<dim3(8,64), 256, 0, stream>>>(hsb, wvT, vraw, nullptr, 8192, 1024, 1024);
  // 5. conv + silu + l2norm
  conv_silu_k<<<8192, 256, 0, stream>>>(qraw, kraw, vraw, cq, ck, cv, vdir, qn, kn);
  // 6. fusion MLP layer 1 (+bias, gelu)
  gemm_bt<1><<<dim3(16,64), 256, 0, stream>>>(hsb, w1T, fus1g, b1, 8192, 2048, 1024);
  // 7. fusion MLP layer 2
  fus2_k<<<1024, 256, 0, stream>>>(fus1g, W2, b2, fusv);
  // 8. UT transform + fragment packing
  ut_k<<<2048, 256, 0, stream>>>(qn, kn, vdir, beta, alocp, updk, wpk, knpk);
  // 9. chunk-serial scan
  scan_k<<<256, 64, 0, stream>>>(qn, wpk, updk, alocp, knpk, delta);
  // 10. FIR + gating + double RMS
  fuse_k<<<1024, 256, 0, stream>>>(vdir, delta, fusv, flo, firs, firl, npf, now, ofin);
  // 11. output projection
  gemm_bt<2><<<dim3(8,64), 256, 0, stream>>>(ofin, woT, d_out, nullptr, 8192, 1024, 1024);
}